// Round 1
// baseline (395.120 us; speedup 1.0000x reference)
//
#include <hip/hip_runtime.h>
#include <math.h>

// OFPenalty: power-iteration eigen-penalty on AAT = W W^T per batch.
// Key insight: never materialize AAT (512x512 per batch). Every use is a
// matvec: AAT x = W (W^T x). 6 double-matvecs total, fp32 throughout.
// A: (64, 512, 28, 28) fp32 -> W: (64, 512, 784). x0: (64, 512, 1).

#define BB 64
#define CC 512
#define DD 784
#define FEPS 1e-12f

// --- workspace layout (floats) ---
// acc[b*16 + k]: k=0 ss0, 1..3 ss1..ss3, 4 ss4, 5 num, 6 den, 7 ss6,
//                8 largest, 9 dotwx, 10 den2
// u:    B*784
// vtmp: B*512   (power-step outputs s1..s3)
// v4:   B*512   (unnormalized x1)
// Mx:   B*512   (AAT x1)
// y:    B*512   (unnormalized x2)

__global__ void k_zero(float* __restrict__ p, int n) {
    int i = blockIdx.x * blockDim.x + threadIdx.x;
    if (i < n) p[i] = 0.0f;
}

__device__ __forceinline__ float block_reduce_256(float s) {
    __shared__ float red[4];
    for (int off = 32; off; off >>= 1) s += __shfl_down(s, off, 64);
    int w = threadIdx.x >> 6;
    if ((threadIdx.x & 63) == 0) red[w] = s;
    __syncthreads();
    return red[0] + red[1] + red[2] + red[3];
}

// ss0 = ||x0_b||^2
__global__ void k_init(const float* __restrict__ x0, float* __restrict__ acc) {
    int b = blockIdx.x;
    const float* x = x0 + (size_t)b * CC;
    float s = 0.0f;
    for (int c = threadIdx.x; c < CC; c += blockDim.x) { float v = x[c]; s += v * v; }
    float t = block_reduce_256(s);
    if (threadIdx.x == 0) acc[b * 16 + 0] = t;
}

// u[b,d] = sum_c A[b,c,d] * (xvec[b,c] / max(sqrt(acc[b,ss_k]), eps))
// grid (4, B) x 256
__global__ void k_at(const float* __restrict__ A, const float* __restrict__ xvec,
                     const float* __restrict__ acc, int ss_k,
                     float* __restrict__ u) {
    int b = blockIdx.y;
    int d = blockIdx.x * blockDim.x + threadIdx.x;
    __shared__ float xs[CC];
    float denom = fmaxf(sqrtf(acc[b * 16 + ss_k]), FEPS);
    for (int c = threadIdx.x; c < CC; c += blockDim.x)
        xs[c] = xvec[(size_t)b * CC + c] / denom;
    __syncthreads();
    if (d >= DD) return;
    const float* ap = A + (size_t)b * CC * DD + d;
    float s = 0.0f;
#pragma unroll 16
    for (int c = 0; c < CC; ++c) s += ap[(size_t)c * DD] * xs[c];
    u[(size_t)b * DD + d] = s;
}

// v[b,c] = sum_d A[b,c,d] * u[b,d]; one wave per row c. grid (128, B) x 256.
// mode 0: acc[k0]     += v^2                       (power-step norm accumulate)
// mode 1: acc[k0]     += v * xn, acc[k0+1] += xn^2 (Rayleigh dot accumulate),
//         xn = xvec2[b,c] / max(sqrt(acc[b,ss_k2]), eps)
__global__ void k_a(const float* __restrict__ A, const float* __restrict__ u,
                    float* __restrict__ vout, float* __restrict__ acc,
                    int mode, int k0,
                    const float* __restrict__ xvec2, int ss_k2) {
    int b = blockIdx.y;
    int wave = threadIdx.x >> 6;
    int lane = threadIdx.x & 63;
    int c = blockIdx.x * 4 + wave;
    const float4* ap = (const float4*)(A + (size_t)(b * CC + c) * DD);
    const float4* up = (const float4*)(u + (size_t)b * DD);
    float s = 0.0f;
#pragma unroll
    for (int k = 0; k < 3; ++k) {
        float4 a4 = ap[lane + 64 * k];
        float4 u4 = up[lane + 64 * k];
        s += a4.x * u4.x + a4.y * u4.y + a4.z * u4.z + a4.w * u4.w;
    }
    if (lane < 4) {  // 196 float4 per row: 3*64 + 4 tail
        float4 a4 = ap[192 + lane];
        float4 u4 = up[192 + lane];
        s += a4.x * u4.x + a4.y * u4.y + a4.z * u4.z + a4.w * u4.w;
    }
    for (int off = 32; off; off >>= 1) s += __shfl_down(s, off, 64);
    __shared__ float p0[4], p1[4];
    if (lane == 0) {
        if (vout) vout[(size_t)b * CC + c] = s;
        if (mode == 0) {
            p0[wave] = s * s; p1[wave] = 0.0f;
        } else {
            float denom2 = fmaxf(sqrtf(acc[b * 16 + ss_k2]), FEPS);
            float xn = xvec2[(size_t)b * CC + c] / denom2;
            p0[wave] = s * xn;
            p1[wave] = xn * xn;
        }
    }
    __syncthreads();
    if (threadIdx.x == 0) {
        atomicAdd(&acc[b * 16 + k0], p0[0] + p0[1] + p0[2] + p0[3]);
        if (mode == 1)
            atomicAdd(&acc[b * 16 + k0 + 1], p1[0] + p1[1] + p1[2] + p1[3]);
    }
}

// largest = num/den; y = Mx - largest * x1; ss6 = ||y||^2
__global__ void k_mid(const float* __restrict__ Mx, const float* __restrict__ v4,
                      float* __restrict__ acc, float* __restrict__ y) {
    int b = blockIdx.x;
    float num = acc[b * 16 + 5], den = acc[b * 16 + 6];
    float largest = num / den;
    float denom4 = fmaxf(sqrtf(acc[b * 16 + 4]), FEPS);
    float s = 0.0f;
    for (int c = threadIdx.x; c < CC; c += blockDim.x) {
        float x1 = v4[(size_t)b * CC + c] / denom4;
        float yy = Mx[(size_t)b * CC + c] - largest * x1;
        y[(size_t)b * CC + c] = yy;
        s += yy * yy;
    }
    float t = block_reduce_256(s);
    if (threadIdx.x == 0) { acc[b * 16 + 7] = t; acc[b * 16 + 8] = largest; }
}

// per-batch penalty, mean over batch
__global__ void k_final(const float* __restrict__ acc, float* __restrict__ out) {
    int b = threadIdx.x;  // 64 threads = 1 wave
    float largest = acc[b * 16 + 8];
    float dotwx   = acc[b * 16 + 9];
    float den2    = acc[b * 16 + 10];
    float tmp = (dotwx - largest * den2) / den2;  // Rayleigh of (AAT - largest I) at x2
    float smallest = tmp + largest;
    float r = largest / smallest - 1.0f;
    float pen = r * r;  // BETA = 1
    for (int off = 32; off; off >>= 1) pen += __shfl_down(pen, off, 64);
    if (b == 0) out[0] = pen / (float)BB;
}

extern "C" void kernel_launch(void* const* d_in, const int* in_sizes, int n_in,
                              void* d_out, int out_size, void* d_ws, size_t ws_size,
                              hipStream_t stream) {
    const float* A  = (const float*)d_in[0];
    const float* x0 = (const float*)d_in[1];
    float* out = (float*)d_out;
    float* ws = (float*)d_ws;

    float* acc  = ws;            // 1024
    float* u    = ws + 1024;     // 50176
    float* vtmp = ws + 51200;    // 32768
    float* v4   = ws + 83968;    // 32768
    float* Mx   = ws + 116736;   // 32768
    float* y    = ws + 149504;   // 32768  (total 182272 floats = 729 KB)

    dim3 gAT(4, BB), gA(CC / 4, BB);

    k_zero<<<4, 256, 0, stream>>>(acc, 1024);
    k_init<<<BB, 256, 0, stream>>>(x0, acc);

    // 3 no-grad power steps: xi = normalize(AAT xi)
    k_at<<<gAT, 256, 0, stream>>>(A, x0,   acc, 0, u);
    k_a <<<gA,  256, 0, stream>>>(A, u, vtmp, acc, 0, 1, nullptr, 0);
    k_at<<<gAT, 256, 0, stream>>>(A, vtmp, acc, 1, u);
    k_a <<<gA,  256, 0, stream>>>(A, u, vtmp, acc, 0, 2, nullptr, 0);
    k_at<<<gAT, 256, 0, stream>>>(A, vtmp, acc, 2, u);
    k_a <<<gA,  256, 0, stream>>>(A, u, vtmp, acc, 0, 3, nullptr, 0);

    // x1 (unnormalized v4, norm^2 in ss4)
    k_at<<<gAT, 256, 0, stream>>>(A, vtmp, acc, 3, u);
    k_a <<<gA,  256, 0, stream>>>(A, u, v4,   acc, 0, 4, nullptr, 0);

    // Mx = AAT x1;  num = <Mx,x1>, den = <x1,x1>
    k_at<<<gAT, 256, 0, stream>>>(A, v4,   acc, 4, u);
    k_a <<<gA,  256, 0, stream>>>(A, u, Mx,   acc, 1, 5, v4, 4);

    // largest; y = Mx - largest*x1; ss6
    k_mid<<<BB, 256, 0, stream>>>(Mx, v4, acc, y);

    // w = AAT x2;  dotwx = <w,x2>, den2 = <x2,x2>
    k_at<<<gAT, 256, 0, stream>>>(A, y, acc, 7, u);
    k_a <<<gA,  256, 0, stream>>>(A, u, nullptr, acc, 1, 9, y, 7);

    k_final<<<1, 64, 0, stream>>>(acc, out);
}

// Round 2
// 365.803 us; speedup vs baseline: 1.0801x; 1.0801x over previous
//
#include <hip/hip_runtime.h>
#include <math.h>

// OFPenalty: power-iteration eigen-penalty on AAT = W W^T per batch, never
// materializing AAT. Round 2: fuse each double-matvec v = W(W^T x_hat) into
// ONE pass over A: each block owns a 512x32 d-column tile of A[b], stages it
// in LDS, computes u_d = <A[:,d], x_hat>, then the partial v_c from the same
// tile, atomicAdd into v. 6 passes over A (617 MB) instead of 12.
// A: (64, 512, 28, 28) fp32 -> W: (64, 512, 784). x0: (64, 512, 1).

#define BB 64
#define CC 512
#define DD 784
#define DCH 32
#define NCH 25          // 24 full chunks of 32 + 1 tail of 16 (784 = 24*32+16)
#define FEPS 1e-12f

__global__ void k_zero(float* __restrict__ p, int n) {
    int i = blockIdx.x * 256 + threadIdx.x;
    if (i < n) p[i] = 0.0f;
}

__device__ __forceinline__ float blk_reduce(float s, float* red) {
    for (int off = 32; off; off >>= 1) s += __shfl_down(s, off, 64);
    int w = threadIdx.x >> 6;
    if ((threadIdx.x & 63) == 0) red[w] = s;
    __syncthreads();
    float t = red[0] + red[1] + red[2] + red[3];
    __syncthreads();                       // allow red[] reuse by caller
    return t;
}

// v_out[b] += partial of AAT_b * normalize(x_in[b]); one block = (chunk, b).
__global__ __launch_bounds__(256, 2)
void k_step(const float* __restrict__ A, const float* __restrict__ xin,
            float* __restrict__ vout) {
    __shared__ float  xs[CC];
    __shared__ float  tile[CC * DCH];      // 64 KB
    __shared__ float4 up[256];
    __shared__ float  usd[DCH];
    __shared__ float  red[4];

    int b = blockIdx.y;
    int chunk = blockIdx.x;
    int d0 = chunk * DCH;
    int dch = (chunk == NCH - 1) ? (DD - d0) : DCH;   // 16 on tail

    // ---- phase A: normalize input (recomputed per block; 512 reads, cheap)
    const float* xp = xin + (size_t)b * CC;
    float xv0 = xp[threadIdx.x], xv1 = xp[threadIdx.x + 256];
    float ss = blk_reduce(xv0 * xv0 + xv1 * xv1, red);
    float rn = 1.0f / fmaxf(sqrtf(ss), FEPS);
    xs[threadIdx.x] = xv0 * rn;
    xs[threadIdx.x + 256] = xv1 * rn;
    __syncthreads();

    // ---- phase B: stream tile from HBM (float4, coalesced), stage in LDS,
    //      accumulate per-thread partial of u_d = <A[:,d], x_hat>
    int lw = (dch == DCH) ? 3 : 2;         // W = dch/4 lanes per row
    int W = 1 << lw;
    int widx = threadIdx.x & (W - 1);
    int r = threadIdx.x >> lw;
    int rows = 256 >> lw;                  // rows per iteration (32 or 64)
    const float4* Ap = (const float4*)(A + (size_t)b * CC * DD);
    int f4base = d0 >> 2;                  // DD/4 = 196 float4 per row
    float4 uacc = make_float4(0.f, 0.f, 0.f, 0.f);
#pragma unroll 4
    for (int c = r; c < CC; c += rows) {
        float4 a4 = Ap[(size_t)c * 196 + f4base + widx];
        ((float4*)tile)[c * W + widx] = a4;
        float x = xs[c];
        uacc.x += a4.x * x; uacc.y += a4.y * x;
        uacc.z += a4.z * x; uacc.w += a4.w * x;
    }
    up[threadIdx.x] = uacc;
    __syncthreads();

    // reduce u partials: thread d (< dch) sums over the row-groups
    if (threadIdx.x < dch) {
        int g = threadIdx.x >> 2, comp = threadIdx.x & 3;
        float s2 = 0.0f;
        for (int rr = 0; rr < rows; rr++) {
            float4 p = up[rr * W + g];
            s2 += comp == 0 ? p.x : comp == 1 ? p.y : comp == 2 ? p.z : p.w;
        }
        usd[threadIdx.x] = s2;
    }
    __syncthreads();

    // ---- phase C: partial v_c = sum_d tile[c][d] * u_d from LDS, atomic out.
    //      d staggered by lane -> 2-way bank alias (free).
    int lane = threadIdx.x & 63;
    int c0 = threadIdx.x, c1 = threadIdx.x + 256;
    float v0 = 0.0f, v1 = 0.0f;
    for (int k = 0; k < dch; k++) {
        int d = (k + lane) & (dch - 1);
        float ud = usd[d];
        v0 += tile[c0 * dch + d] * ud;
        v1 += tile[c1 * dch + d] * ud;
    }
    float* vp = vout + (size_t)b * CC;
    atomicAdd(&vp[c0], v0);
    atomicAdd(&vp[c1], v1);
}

// largest_b = <t5, x1>/<x1,x1>, x1 = t4/||t4||;  y = t5 - largest*x1
__global__ void k_mid(const float* __restrict__ t4, const float* __restrict__ t5,
                      float* __restrict__ acc, float* __restrict__ y) {
    __shared__ float red[4];
    int b = blockIdx.x;
    const float* p4 = t4 + (size_t)b * CC;
    const float* p5 = t5 + (size_t)b * CC;
    float a0 = p4[threadIdx.x], a1 = p4[threadIdx.x + 256];
    float b0 = p5[threadIdx.x], b1 = p5[threadIdx.x + 256];
    float ss4 = blk_reduce(a0 * a0 + a1 * a1, red);
    float rn = 1.0f / fmaxf(sqrtf(ss4), FEPS);
    float x10 = a0 * rn, x11 = a1 * rn;
    float num = blk_reduce(b0 * x10 + b1 * x11, red);
    float den = blk_reduce(x10 * x10 + x11 * x11, red);
    float largest = num / den;
    float* yp = y + (size_t)b * CC;
    yp[threadIdx.x] = b0 - largest * x10;
    yp[threadIdx.x + 256] = b1 - largest * x11;
    if (threadIdx.x == 0) acc[b * 8 + 0] = largest;
}

// dotwx = <w, x2>, den2 = <x2,x2>, x2 = y/||y||
__global__ void k_fin2(const float* __restrict__ w, const float* __restrict__ y,
                       float* __restrict__ acc) {
    __shared__ float red[4];
    int b = blockIdx.x;
    const float* wp = w + (size_t)b * CC;
    const float* yp = y + (size_t)b * CC;
    float w0 = wp[threadIdx.x], w1 = wp[threadIdx.x + 256];
    float y0 = yp[threadIdx.x], y1 = yp[threadIdx.x + 256];
    float ssy = blk_reduce(y0 * y0 + y1 * y1, red);
    float rn = 1.0f / fmaxf(sqrtf(ssy), FEPS);
    float x20 = y0 * rn, x21 = y1 * rn;
    float dotwx = blk_reduce(w0 * x20 + w1 * x21, red);
    float den2 = blk_reduce(x20 * x20 + x21 * x21, red);
    if (threadIdx.x == 0) { acc[b * 8 + 1] = dotwx; acc[b * 8 + 2] = den2; }
}

__global__ void k_out(const float* __restrict__ acc, float* __restrict__ out) {
    int b = threadIdx.x;                   // 64 threads = 1 wave
    float largest = acc[b * 8 + 0];
    float dotwx   = acc[b * 8 + 1];
    float den2    = acc[b * 8 + 2];
    float tmp = (dotwx - largest * den2) / den2;
    float smallest = tmp + largest;
    float r = largest / smallest - 1.0f;
    float pen = r * r;                     // BETA = 1
    for (int off = 32; off; off >>= 1) pen += __shfl_down(pen, off, 64);
    if (b == 0) out[0] = pen / (float)BB;
}

extern "C" void kernel_launch(void* const* d_in, const int* in_sizes, int n_in,
                              void* d_out, int out_size, void* d_ws, size_t ws_size,
                              hipStream_t stream) {
    const float* A  = (const float*)d_in[0];
    const float* x0 = (const float*)d_in[1];
    float* out = (float*)d_out;
    float* ws = (float*)d_ws;

    float* acc = ws;                 // 512 floats (64 x 8)
    float* t1  = ws + 512;           // each buffer BB*CC = 32768 floats
    float* t2  = t1 + BB * CC;
    float* t3  = t2 + BB * CC;
    float* t4  = t3 + BB * CC;       // unnormalized x1
    float* t5  = t4 + BB * CC;       // Mx = AAT x1
    float* w   = t5 + BB * CC;       // AAT x2
    float* y   = w  + BB * CC;       // unnormalized x2 (direct store, no zero)

    // zero the 6 atomic-accumulated buffers (t1..t5, w)
    int nz = 6 * BB * CC;
    k_zero<<<(nz + 255) / 256, 256, 0, stream>>>(t1, nz);

    dim3 gS(NCH, BB);
    k_step<<<gS, 256, 0, stream>>>(A, x0, t1);   // t1 = AAT x^0
    k_step<<<gS, 256, 0, stream>>>(A, t1, t2);   // t2 = AAT x^1
    k_step<<<gS, 256, 0, stream>>>(A, t2, t3);   // t3 = AAT x^2
    k_step<<<gS, 256, 0, stream>>>(A, t3, t4);   // t4 = AAT x^3  (x1 = t4^)
    k_step<<<gS, 256, 0, stream>>>(A, t4, t5);   // t5 = AAT x1   (Mx)

    k_mid<<<BB, 256, 0, stream>>>(t4, t5, acc, y);

    k_step<<<gS, 256, 0, stream>>>(A, y, w);     // w = AAT x2

    k_fin2<<<BB, 256, 0, stream>>>(w, y, acc);
    k_out<<<1, 64, 0, stream>>>(acc, out);
}